// Round 8
// baseline (610.832 us; speedup 1.0000x reference)
//
#include <hip/hip_runtime.h>
#include <stdint.h>

#define B_ 4
#define C_ 256
#define N_ 4096
#define TK 32

using floatx4 = __attribute__((ext_vector_type(4))) float;
using halfx8  = __attribute__((ext_vector_type(8))) _Float16;

__device__ __forceinline__ float bf16_to_f(uint16_t u) {
    union { uint32_t u; float f; } c; c.u = ((uint32_t)u) << 16; return c.f;
}
__device__ __forceinline__ uint16_t f_to_bf16(float f) {
    union { float f; uint32_t u; } c; c.f = f;
    uint32_t u = c.u;
    u += 0x7FFFu + ((u >> 16) & 1u);   // RNE
    return (uint16_t)(u >> 16);
}

// ---------------- sniff input dtype (1 = f32, 0 = bf16) ----------------
__global__ void sniff_kernel(const uint16_t* __restrict__ wq_u16, int* __restrict__ flag) {
    __shared__ int cnt;
    if (threadIdx.x == 0) cnt = 0;
    __syncthreads();
    int local = 0;
    for (int i = threadIdx.x; i < 8192; i += 256) {
        int e = (wq_u16[i] >> 7) & 0xFF;
        if (e >= 132) local++;
    }
    atomicAdd(&cnt, local);
    __syncthreads();
    if (threadIdx.x == 0) *flag = (cnt > 64) ? 1 : 0;
}

// ---------------- W -> f16 ----------------
__global__ void wconv_kernel(const void* __restrict__ wq,
                             const void* __restrict__ wk,
                             const void* __restrict__ wv,
                             _Float16* __restrict__ wf,
                             const int* __restrict__ flag) {
    const int isf32 = *flag;
    int idx = blockIdx.x * 256 + threadIdx.x;
    int mat = idx >> 16;
    int off = idx & 65535;
    const void* src = (mat == 0) ? wq : ((mat == 1) ? wk : wv);
    float v = isf32 ? ((const float*)src)[off] : bf16_to_f(((const uint16_t*)src)[off]);
    wf[idx] = (_Float16)v;
}

// ---------------- QKV projection (MFMA f16), mat = blockIdx.z ----------------
__global__ __launch_bounds__(256) void proj_kernel(
    const void* __restrict__ x_raw,      // (B,C,N) bf16 or f32
    const _Float16* __restrict__ wf,     // 3 x (C,C) f16
    _Float16* __restrict__ qt,           // (B,N,C)
    _Float16* __restrict__ kt,           // (B,N,C)
    _Float16* __restrict__ v,            // (B,C,N)
    const int* __restrict__ flag) {
    const int isf32 = *flag;
    const int b = blockIdx.y;
    const int mat = blockIdx.z;
    const int n0 = blockIdx.x * 64;
    const int tid = threadIdx.x;
    const int w = tid >> 6;
    const int L = tid & 63;
    const int lane15 = L & 15;
    const int quad = L >> 4;
    const int n = n0 + w * 16 + lane15;

    halfx8 bfrag[8];
    const size_t xbase = (size_t)b * C_ * N_;
    if (isf32) {
        const float* xb = (const float*)x_raw + xbase;
#pragma unroll
        for (int cs = 0; cs < 8; ++cs) {
            const int cbase = cs * 32 + quad * 8;
            halfx8 f;
#pragma unroll
            for (int j = 0; j < 8; ++j)
                f[j] = (_Float16)xb[(size_t)(cbase + j) * N_ + n];
            bfrag[cs] = f;
        }
    } else {
        const uint16_t* xb = (const uint16_t*)x_raw + xbase;
#pragma unroll
        for (int cs = 0; cs < 8; ++cs) {
            const int cbase = cs * 32 + quad * 8;
            halfx8 f;
#pragma unroll
            for (int j = 0; j < 8; ++j)
                f[j] = (_Float16)bf16_to_f(xb[(size_t)(cbase + j) * N_ + n]);
            bfrag[cs] = f;
        }
    }

    const _Float16* wm = wf + mat * (C_ * C_);
#pragma unroll 4
    for (int ot = 0; ot < 16; ++ot) {
        const int obase = ot * 16;
        floatx4 acc = {0.f, 0.f, 0.f, 0.f};
        const _Float16* wrow = wm + (size_t)(obase + lane15) * C_ + quad * 8;
#pragma unroll
        for (int cs = 0; cs < 8; ++cs) {
            halfx8 af = *(const halfx8*)(wrow + cs * 32);
            acc = __builtin_amdgcn_mfma_f32_16x16x32_f16(af, bfrag[cs], acc, 0, 0, 0);
        }
        if (mat < 2) {
            _Float16* dst = (mat == 0 ? qt : kt) +
                            ((size_t)b * N_ + n) * C_ + obase + quad * 4;
            union { _Float16 h[4]; unsigned long long u64; } pk;
#pragma unroll
            for (int r = 0; r < 4; ++r) pk.h[r] = (_Float16)acc[r];
            *(unsigned long long*)dst = pk.u64;
        } else {
            _Float16* dst = v + ((size_t)b * C_ + obase + quad * 4) * N_ + n;
#pragma unroll
            for (int r = 0; r < 4; ++r) dst[(size_t)r * N_] = (_Float16)acc[r];
        }
    }
}

// ---------------- flash attention: Qtile=128, 8 waves, 512 blocks (2/CU) ----------------
// r5's proven k-loop + churn-free epilogue: o_acc routed through LDS (Obuf) so
// O_part is written as full-sector coalesced NT streams (no write RMW -> no L2
// churn -> K/V stays L2-resident, the r7-discovered condition for reuse).
// Swizzle: l = (combo&7) + 8*qt + 256*(combo>>3), combo = b*4+ks.
__global__ __launch_bounds__(512, 4) void attn_kernel(
    const _Float16* __restrict__ qt,     // (B,N,C)
    const _Float16* __restrict__ kt,     // (B,N,C)
    const _Float16* __restrict__ v,      // (B,C,N)
    _Float16* __restrict__ O_part,       // [b][qt32][ks4][q128][c256] f16
    float* __restrict__ m_part,          // [b][qt32][ks4][q128]
    float* __restrict__ l_part) {
    const int l = blockIdx.x;
    const int combo = (l & 7) | ((l >> 8) << 3);
    const int qt_i = (l >> 3) & 31;
    const int b = combo >> 2;
    const int ks = combo & 3;
    const int q0 = qt_i * 128;
    const int tid = threadIdx.x;
    const int w = tid >> 6;              // 0..7
    const int L = tid & 63;
    const int lane15 = L & 15;
    const int quad = L >> 4;

    __shared__ _Float16 Kt_s[TK][260];   // 2-way banks max (free)
    __shared__ _Float16 Vs[C_][36];
    __shared__ _Float16 Ps[8][16][36];
    __shared__ float alpha_s[8][16];
    __shared__ _Float16 Obuf[128][72];   // epilogue transpose; 144 B rows (16B-aligned)

    // Q A-frags: A[m=q][k=c], q = q0 + w*16 + lane15
    halfx8 qfrag[8];
    {
        const _Float16* qrow = qt + ((size_t)b * N_ + q0 + w * 16 + lane15) * C_ + quad * 8;
#pragma unroll
        for (int cs = 0; cs < 8; ++cs)
            qfrag[cs] = __builtin_nontemporal_load((const halfx8*)(qrow + cs * 32));
    }

    floatx4 o_acc[16];
#pragma unroll
    for (int i = 0; i < 16; ++i) o_acc[i] = (floatx4){0.f, 0.f, 0.f, 0.f};
    float m_r[4], l_r[4];
#pragma unroll
    for (int r = 0; r < 4; ++r) { m_r[r] = -1e30f; l_r[r] = 0.f; }

    const _Float16* ktb = kt + (size_t)b * N_ * C_;
    const _Float16* vb  = v  + (size_t)b * C_ * N_;

    const int kbeg = ks * 1024;
    for (int k0 = kbeg; k0 < kbeg + 1024; k0 += TK) {
        // ---- stage K (32 x 256) and V (256 x 32) ----
#pragma unroll
        for (int p = 0; p < 2; ++p) {
            int idx = p * 512 + tid;
            int key = idx >> 5;
            int ch  = idx & 31;
            *(halfx8*)(&Kt_s[key][ch * 8]) =
                *(const halfx8*)(ktb + (size_t)(k0 + key) * C_ + ch * 8);
        }
#pragma unroll
        for (int p = 0; p < 2; ++p) {
            int idx = p * 512 + tid;
            int c  = idx >> 2;
            int ch = idx & 3;
            *(halfx8*)(&Vs[c][ch * 8]) =
                *(const halfx8*)(vb + (size_t)c * N_ + k0 + ch * 8);
        }
        __syncthreads();

        // ---- S = Q K^T ----
        floatx4 s_acc[2];
        s_acc[0] = (floatx4){0.f, 0.f, 0.f, 0.f};
        s_acc[1] = (floatx4){0.f, 0.f, 0.f, 0.f};
#pragma unroll
        for (int ktile = 0; ktile < 2; ++ktile) {
            const _Float16* krow = &Kt_s[ktile * 16 + lane15][quad * 8];
#pragma unroll
            for (int cs = 0; cs < 8; ++cs) {
                halfx8 bf = *(const halfx8*)(krow + cs * 32);
                s_acc[ktile] = __builtin_amdgcn_mfma_f32_16x16x32_f16(qfrag[cs], bf, s_acc[ktile], 0, 0, 0);
            }
        }

        // ---- online softmax (wave-local) ----
        float rmax[4], psum[4], p0[4], p1[4], alpha[4];
#pragma unroll
        for (int r = 0; r < 4; ++r) rmax[r] = fmaxf(s_acc[0][r], s_acc[1][r]);
#pragma unroll
        for (int mask = 1; mask <= 8; mask <<= 1)
#pragma unroll
            for (int r = 0; r < 4; ++r) rmax[r] = fmaxf(rmax[r], __shfl_xor(rmax[r], mask));
#pragma unroll
        for (int r = 0; r < 4; ++r) {
            float mn = fmaxf(m_r[r], rmax[r]);
            alpha[r] = __expf(m_r[r] - mn);
            m_r[r] = mn;
            p0[r] = __expf(s_acc[0][r] - mn);
            p1[r] = __expf(s_acc[1][r] - mn);
            psum[r] = p0[r] + p1[r];
        }
#pragma unroll
        for (int mask = 1; mask <= 8; mask <<= 1)
#pragma unroll
            for (int r = 0; r < 4; ++r) psum[r] += __shfl_xor(psum[r], mask);
#pragma unroll
        for (int r = 0; r < 4; ++r) l_r[r] = l_r[r] * alpha[r] + psum[r];

        // ---- P/alpha -> LDS; wave-local: no barrier ----
#pragma unroll
        for (int r = 0; r < 4; ++r) {
            Ps[w][quad * 4 + r][lane15]      = (_Float16)p0[r];
            Ps[w][quad * 4 + r][16 + lane15] = (_Float16)p1[r];
        }
        if (lane15 == 0) {
#pragma unroll
            for (int r = 0; r < 4; ++r) alpha_s[w][quad * 4 + r] = alpha[r];
        }

        // ---- O *= alpha; O += V P^T ----
        float av = alpha_s[w][lane15];
#pragma unroll
        for (int i = 0; i < 16; ++i) {
            o_acc[i][0] *= av; o_acc[i][1] *= av; o_acc[i][2] *= av; o_acc[i][3] *= av;
        }
        halfx8 pfrag = *(const halfx8*)(&Ps[w][lane15][quad * 8]);
#pragma unroll
        for (int ct = 0; ct < 16; ++ct) {
            halfx8 vf = *(const halfx8*)(&Vs[ct * 16 + lane15][quad * 8]);
            o_acc[ct] = __builtin_amdgcn_mfma_f32_16x16x32_f16(vf, pfrag, o_acc[ct], 0, 0, 0);
        }
        __syncthreads();
    }

    // ---- epilogue: transpose via Obuf -> coalesced full-sector NT O_part stores ----
    // o_acc[ct][r] = O[c = ct*16 + quad*4 + r][q_local = w*16 + lane15]
    const size_t pbase = (size_t)((b * 32 + qt_i) * 4 + ks);
    for (int cg = 0; cg < 4; ++cg) {
#pragma unroll
        for (int i = 0; i < 4; ++i) {
            int ct = cg * 4 + i;
            union { _Float16 h[4]; unsigned long long u64; } pk;
#pragma unroll
            for (int r = 0; r < 4; ++r) pk.h[r] = (_Float16)o_acc[ct][r];
            *(unsigned long long*)(&Obuf[w * 16 + lane15][i * 16 + quad * 4]) = pk.u64;
        }
        __syncthreads();
        {
            int q = tid >> 2, seg = tid & 3;   // 128 rows x 4 segs of 32 B
            const _Float16* src = &Obuf[q][seg * 16];
            _Float16* dst = O_part + (pbase * 128 + q) * 256 + cg * 64 + seg * 16;
            halfx8 v0 = *(const halfx8*)src;
            halfx8 v1 = *(const halfx8*)(src + 8);
            __builtin_nontemporal_store(v0, (halfx8*)dst);
            __builtin_nontemporal_store(v1, (halfx8*)(dst + 8));
        }
        __syncthreads();
    }
    if (lane15 == 0) {
        float* mb = m_part + pbase * 128 + w * 16 + quad * 4;
        float* lb = l_part + pbase * 128 + w * 16 + quad * 4;
#pragma unroll
        for (int r = 0; r < 4; ++r) { mb[r] = m_r[r]; lb[r] = l_r[r]; }
    }
}

// ---------------- combine partials + epilogue (r5-proven shape, 128-q strides) ----
__global__ __launch_bounds__(256) void reduce_kernel(
    const void* __restrict__ x_raw,
    const _Float16* __restrict__ O_part, // [b][qt32][ks4][q128][c256]
    const float* __restrict__ m_part,
    const float* __restrict__ l_part,
    const void* __restrict__ gamma_p,
    void* __restrict__ out,
    const int* __restrict__ flag) {
    const int isf32 = *flag;
    const int b = blockIdx.y;
    const int tid = threadIdx.x;
    const int q = tid & 63;        // lane -> coalesced n
    const int wv = tid >> 6;       // wave -> c range
    const int n = blockIdx.x * 64 + q;
    const int qt_i = n >> 7;
    const int qq = n & 127;

    const size_t sbase = (size_t)(b * 32 + qt_i) * 4;
    float m0 = m_part[(sbase + 0) * 128 + qq], m1 = m_part[(sbase + 1) * 128 + qq],
          m2 = m_part[(sbase + 2) * 128 + qq], m3 = m_part[(sbase + 3) * 128 + qq];
    float l0 = l_part[(sbase + 0) * 128 + qq], l1 = l_part[(sbase + 1) * 128 + qq],
          l2 = l_part[(sbase + 2) * 128 + qq], l3 = l_part[(sbase + 3) * 128 + qq];
    float M = fmaxf(fmaxf(m0, m1), fmaxf(m2, m3));
    float w0 = __expf(m0 - M), w1 = __expf(m1 - M), w2 = __expf(m2 - M), w3 = __expf(m3 - M);
    float denom = w0 * l0 + w1 * l1 + w2 * l2 + w3 * l3;
    float g = isf32 ? ((const float*)gamma_p)[0] : bf16_to_f(((const uint16_t*)gamma_p)[0]);
    float s = g / denom;

    const _Float16* o0 = O_part + sbase * 32768 + (size_t)qq * 256;
#pragma unroll
    for (int ch = 0; ch < 8; ++ch) {
        const int c0 = wv * 64 + ch * 8;
        halfx8 a     = __builtin_nontemporal_load((const halfx8*)(o0 + c0));
        halfx8 bpart = __builtin_nontemporal_load((const halfx8*)(o0 + 32768 + c0));
        halfx8 cpart = __builtin_nontemporal_load((const halfx8*)(o0 + 65536 + c0));
        halfx8 dpart = __builtin_nontemporal_load((const halfx8*)(o0 + 98304 + c0));
#pragma unroll
        for (int j = 0; j < 8; ++j) {
            float acc = w0 * (float)a[j] + w1 * (float)bpart[j]
                      + w2 * (float)cpart[j] + w3 * (float)dpart[j];
            size_t off = ((size_t)b * 256 + c0 + j) * 4096 + n;
            float xv = isf32 ? __builtin_nontemporal_load((const float*)x_raw + off)
                             : bf16_to_f(((const uint16_t*)x_raw)[off]);
            float val = s * acc + xv;
            if (isf32) __builtin_nontemporal_store(val, (float*)out + off);
            else ((uint16_t*)out)[off] = f_to_bf16(val);
        }
    }
}

// ---------------- fallback: monolithic attn (small ws) ----------------
__global__ __launch_bounds__(256, 2) void attn_full_kernel(
    const void* __restrict__ x_raw,
    const _Float16* __restrict__ qt,
    const _Float16* __restrict__ kt,
    const _Float16* __restrict__ v,
    const void* __restrict__ gamma_p,
    void* __restrict__ out,
    const int* __restrict__ flag) {
    const int isf32 = *flag;
    const int b = blockIdx.y;
    const int q0 = blockIdx.x * 64;
    const int tid = threadIdx.x;
    const int w = tid >> 6;
    const int L = tid & 63;
    const int lane15 = L & 15;
    const int quad = L >> 4;

    __shared__ _Float16 Kt_s[TK][260];
    __shared__ _Float16 Vs[C_][36];
    __shared__ _Float16 Ps[4][16][36];
    __shared__ float alpha_s[4][16];
    __shared__ float l_s[4][16];

    halfx8 qfrag[8];
    {
        const _Float16* qrow = qt + ((size_t)b * N_ + q0 + w * 16 + lane15) * C_ + quad * 8;
#pragma unroll
        for (int cs = 0; cs < 8; ++cs) qfrag[cs] = *(const halfx8*)(qrow + cs * 32);
    }
    floatx4 o_acc[16];
#pragma unroll
    for (int i = 0; i < 16; ++i) o_acc[i] = (floatx4){0.f, 0.f, 0.f, 0.f};
    float m_r[4], l_r[4];
#pragma unroll
    for (int r = 0; r < 4; ++r) { m_r[r] = -1e30f; l_r[r] = 0.f; }
    const _Float16* ktb = kt + (size_t)b * N_ * C_;
    const _Float16* vb  = v  + (size_t)b * C_ * N_;

    for (int k0 = 0; k0 < N_; k0 += TK) {
#pragma unroll
        for (int p = 0; p < 4; ++p) {
            int idx = p * 256 + tid;
            int key = idx >> 5, ch = idx & 31;
            *(halfx8*)(&Kt_s[key][ch * 8]) =
                *(const halfx8*)(ktb + (size_t)(k0 + key) * C_ + ch * 8);
        }
#pragma unroll
        for (int p = 0; p < 4; ++p) {
            int idx = p * 256 + tid;
            int c = idx >> 2, ch = idx & 3;
            *(halfx8*)(&Vs[c][ch * 8]) =
                *(const halfx8*)(vb + (size_t)c * N_ + k0 + ch * 8);
        }
        __syncthreads();
        floatx4 s_acc[2];
        s_acc[0] = (floatx4){0.f, 0.f, 0.f, 0.f};
        s_acc[1] = (floatx4){0.f, 0.f, 0.f, 0.f};
#pragma unroll
        for (int ktile = 0; ktile < 2; ++ktile) {
            const _Float16* krow = &Kt_s[ktile * 16 + lane15][quad * 8];
#pragma unroll
            for (int cs = 0; cs < 8; ++cs) {
                halfx8 bf = *(const halfx8*)(krow + cs * 32);
                s_acc[ktile] = __builtin_amdgcn_mfma_f32_16x16x32_f16(qfrag[cs], bf, s_acc[ktile], 0, 0, 0);
            }
        }
        float rmax[4], psum[4], p0[4], p1[4], alpha[4];
#pragma unroll
        for (int r = 0; r < 4; ++r) rmax[r] = fmaxf(s_acc[0][r], s_acc[1][r]);
#pragma unroll
        for (int mask = 1; mask <= 8; mask <<= 1)
#pragma unroll
            for (int r = 0; r < 4; ++r) rmax[r] = fmaxf(rmax[r], __shfl_xor(rmax[r], mask));
#pragma unroll
        for (int r = 0; r < 4; ++r) {
            float mn = fmaxf(m_r[r], rmax[r]);
            alpha[r] = __expf(m_r[r] - mn);
            m_r[r] = mn;
            p0[r] = __expf(s_acc[0][r] - mn);
            p1[r] = __expf(s_acc[1][r] - mn);
            psum[r] = p0[r] + p1[r];
        }
#pragma unroll
        for (int mask = 1; mask <= 8; mask <<= 1)
#pragma unroll
            for (int r = 0; r < 4; ++r) psum[r] += __shfl_xor(psum[r], mask);
#pragma unroll
        for (int r = 0; r < 4; ++r) l_r[r] = l_r[r] * alpha[r] + psum[r];
#pragma unroll
        for (int r = 0; r < 4; ++r) {
            Ps[w][quad * 4 + r][lane15]      = (_Float16)p0[r];
            Ps[w][quad * 4 + r][16 + lane15] = (_Float16)p1[r];
        }
        if (lane15 == 0) {
#pragma unroll
            for (int r = 0; r < 4; ++r) alpha_s[w][quad * 4 + r] = alpha[r];
        }
        __syncthreads();
        float av = alpha_s[w][lane15];
#pragma unroll
        for (int i = 0; i < 16; ++i) {
            o_acc[i][0] *= av; o_acc[i][1] *= av; o_acc[i][2] *= av; o_acc[i][3] *= av;
        }
        halfx8 pfrag = *(const halfx8*)(&Ps[w][lane15][quad * 8]);
#pragma unroll
        for (int ct = 0; ct < 16; ++ct) {
            halfx8 vf = *(const halfx8*)(&Vs[ct * 16 + lane15][quad * 8]);
            o_acc[ct] = __builtin_amdgcn_mfma_f32_16x16x32_f16(vf, pfrag, o_acc[ct], 0, 0, 0);
        }
        __syncthreads();
    }
    if (lane15 == 0) {
#pragma unroll
        for (int r = 0; r < 4; ++r) l_s[w][quad * 4 + r] = l_r[r];
    }
    __syncthreads();
    float linv = 1.0f / l_s[w][lane15];
    float g = isf32 ? ((const float*)gamma_p)[0] : bf16_to_f(((const uint16_t*)gamma_p)[0]);
    const int n_out = q0 + w * 16 + lane15;
#pragma unroll
    for (int ct = 0; ct < 16; ++ct)
#pragma unroll
        for (int r = 0; r < 4; ++r) {
            int c = ct * 16 + quad * 4 + r;
            size_t off = ((size_t)b * C_ + c) * N_ + n_out;
            float val = g * o_acc[ct][r] * linv +
                        (isf32 ? ((const float*)x_raw)[off] : bf16_to_f(((const uint16_t*)x_raw)[off]));
            if (isf32) ((float*)out)[off] = val;
            else ((uint16_t*)out)[off] = f_to_bf16(val);
        }
}

// ---------------- launcher ----------------
extern "C" void kernel_launch(void* const* d_in, const int* in_sizes, int n_in,
                              void* d_out, int out_size, void* d_ws, size_t ws_size,
                              hipStream_t stream) {
    const void* x  = d_in[0];
    const void* wq = d_in[1];
    const void* wk = d_in[2];
    const void* wv = d_in[3];
    const void* gm = d_in[4];

    char* ws = (char*)d_ws;
    int* flag    = (int*)ws;
    _Float16* wf = (_Float16*)(ws + 4096);
    size_t o0 = 4096 + 393216;
    _Float16* qt = (_Float16*)(ws + o0);
    _Float16* kt = (_Float16*)(ws + o0 + 8388608);
    _Float16* v  = (_Float16*)(ws + o0 + 2 * 8388608);
    size_t o1 = o0 + 3 * 8388608;                       // 25,563,136
    _Float16* opart = (_Float16*)(ws + o1);             // 33,554,432 B
    float* mpart = (float*)(ws + o1 + 33554432);        // 262,144 B
    float* lpart = (float*)(ws + o1 + 33554432 + 262144);
    const size_t need = o1 + 33554432 + 2 * 262144;     // ~59.6 MB

    sniff_kernel<<<dim3(1), dim3(256), 0, stream>>>((const uint16_t*)wq, flag);
    wconv_kernel<<<dim3(768), dim3(256), 0, stream>>>(wq, wk, wv, wf, flag);
    proj_kernel<<<dim3(64, 4, 3), dim3(256), 0, stream>>>(x, wf, qt, kt, v, flag);
    if (ws_size >= need) {
        attn_kernel<<<dim3(512), dim3(512), 0, stream>>>(qt, kt, v, opart, mpart, lpart);
        reduce_kernel<<<dim3(64, 4), dim3(256), 0, stream>>>(x, opart, mpart, lpart, gm, d_out, flag);
    } else {
        attn_full_kernel<<<dim3(64, 4), dim3(256), 0, stream>>>(x, qt, kt, v, gm, d_out, flag);
    }
}

// Round 9
// 290.702 us; speedup vs baseline: 2.1012x; 2.1012x over previous
//
#include <hip/hip_runtime.h>
#include <stdint.h>

#define B_ 4
#define C_ 256
#define N_ 4096
#define TK 32

using floatx4 = __attribute__((ext_vector_type(4))) float;
using halfx8  = __attribute__((ext_vector_type(8))) _Float16;

__device__ __forceinline__ float bf16_to_f(uint16_t u) {
    union { uint32_t u; float f; } c; c.u = ((uint32_t)u) << 16; return c.f;
}
__device__ __forceinline__ uint16_t f_to_bf16(float f) {
    union { float f; uint32_t u; } c; c.f = f;
    uint32_t u = c.u;
    u += 0x7FFFu + ((u >> 16) & 1u);   // RNE
    return (uint16_t)(u >> 16);
}

__device__ __forceinline__ void async_copy16(const void* g, void* l) {
    __builtin_amdgcn_global_load_lds(
        (const __attribute__((address_space(1))) void*)g,
        (__attribute__((address_space(3))) void*)l, 16, 0, 0);
}

// ---------------- sniff input dtype (1 = f32, 0 = bf16) ----------------
__global__ void sniff_kernel(const uint16_t* __restrict__ wq_u16, int* __restrict__ flag) {
    __shared__ int cnt;
    if (threadIdx.x == 0) cnt = 0;
    __syncthreads();
    int local = 0;
    for (int i = threadIdx.x; i < 8192; i += 256) {
        int e = (wq_u16[i] >> 7) & 0xFF;
        if (e >= 132) local++;
    }
    atomicAdd(&cnt, local);
    __syncthreads();
    if (threadIdx.x == 0) *flag = (cnt > 64) ? 1 : 0;
}

// ---------------- W -> f16 ----------------
__global__ void wconv_kernel(const void* __restrict__ wq,
                             const void* __restrict__ wk,
                             const void* __restrict__ wv,
                             _Float16* __restrict__ wf,
                             const int* __restrict__ flag) {
    const int isf32 = *flag;
    int idx = blockIdx.x * 256 + threadIdx.x;
    int mat = idx >> 16;
    int off = idx & 65535;
    const void* src = (mat == 0) ? wq : ((mat == 1) ? wk : wv);
    float v = isf32 ? ((const float*)src)[off] : bf16_to_f(((const uint16_t*)src)[off]);
    wf[idx] = (_Float16)v;
}

// ---------------- QKV projection (MFMA f16), mat = blockIdx.z ----------------
__global__ __launch_bounds__(256) void proj_kernel(
    const void* __restrict__ x_raw,
    const _Float16* __restrict__ wf,
    _Float16* __restrict__ qt,           // (B,N,C)
    _Float16* __restrict__ kt,           // (B,N,C)
    _Float16* __restrict__ v,            // (B,C,N)
    const int* __restrict__ flag) {
    const int isf32 = *flag;
    const int b = blockIdx.y;
    const int mat = blockIdx.z;
    const int n0 = blockIdx.x * 64;
    const int tid = threadIdx.x;
    const int w = tid >> 6;
    const int L = tid & 63;
    const int lane15 = L & 15;
    const int quad = L >> 4;
    const int n = n0 + w * 16 + lane15;

    halfx8 bfrag[8];
    const size_t xbase = (size_t)b * C_ * N_;
    if (isf32) {
        const float* xb = (const float*)x_raw + xbase;
#pragma unroll
        for (int cs = 0; cs < 8; ++cs) {
            const int cbase = cs * 32 + quad * 8;
            halfx8 f;
#pragma unroll
            for (int j = 0; j < 8; ++j)
                f[j] = (_Float16)xb[(size_t)(cbase + j) * N_ + n];
            bfrag[cs] = f;
        }
    } else {
        const uint16_t* xb = (const uint16_t*)x_raw + xbase;
#pragma unroll
        for (int cs = 0; cs < 8; ++cs) {
            const int cbase = cs * 32 + quad * 8;
            halfx8 f;
#pragma unroll
            for (int j = 0; j < 8; ++j)
                f[j] = (_Float16)bf16_to_f(xb[(size_t)(cbase + j) * N_ + n]);
            bfrag[cs] = f;
        }
    }

    const _Float16* wm = wf + mat * (C_ * C_);
#pragma unroll 4
    for (int ot = 0; ot < 16; ++ot) {
        const int obase = ot * 16;
        floatx4 acc = {0.f, 0.f, 0.f, 0.f};
        const _Float16* wrow = wm + (size_t)(obase + lane15) * C_ + quad * 8;
#pragma unroll
        for (int cs = 0; cs < 8; ++cs) {
            halfx8 af = *(const halfx8*)(wrow + cs * 32);
            acc = __builtin_amdgcn_mfma_f32_16x16x32_f16(af, bfrag[cs], acc, 0, 0, 0);
        }
        if (mat < 2) {
            _Float16* dst = (mat == 0 ? qt : kt) +
                            ((size_t)b * N_ + n) * C_ + obase + quad * 4;
            union { _Float16 h[4]; unsigned long long u64; } pk;
#pragma unroll
            for (int r = 0; r < 4; ++r) pk.h[r] = (_Float16)acc[r];
            *(unsigned long long*)dst = pk.u64;
        } else {
            _Float16* dst = v + ((size_t)b * C_ + obase + quad * 4) * N_ + n;
#pragma unroll
            for (int r = 0; r < 4; ++r) dst[(size_t)r * N_] = (_Float16)acc[r];
        }
    }
}

// ---------------- flash attention: Qtile=256, async-dbuf pipeline, S^T softmax ----
// 256 blocks x 1024 thr (1 block/CU: preserves the L2-reuse law).
// K/V staged by global_load_lds into static unpadded dbufs (XOR-swizzled);
// ONE barrier per iter (its vmcnt drain completes the async loads).
// S^T = K*Q -> per-lane row softmax (2 shuffles), alpha lane-local.
__global__ __launch_bounds__(1024) void attn_kernel(
    const _Float16* __restrict__ qt,     // (B,N,C)
    const _Float16* __restrict__ kt,     // (B,N,C)
    const _Float16* __restrict__ v,      // (B,C,N)
    _Float16* __restrict__ O_part,       // [b][qt16][ks4][q256][c256] f16
    float* __restrict__ m_part,          // [b][qt16][ks4][q256]
    float* __restrict__ l_part) {
    const int l = blockIdx.x;
    const int combo = (l & 7) | ((l >> 7) << 3);
    const int qt_i = (l >> 3) & 15;
    const int b = combo >> 2;
    const int ks = combo & 3;
    const int q0 = qt_i * 256;
    const int tid = threadIdx.x;
    const int w = tid >> 6;              // 0..15
    const int L = tid & 63;
    const int lane15 = L & 15;
    const int quad = L >> 4;

    // static LDS (distinct objects -> no alias-forced waits): 4 x 16 KB = 64 KB
    __shared__ _Float16 Kb0[32][256], Kb1[32][256];   // [key][c], chunk ^= (key&7)
    __shared__ _Float16 Vb0[256][32], Vb1[256][32];   // [c][key], chunk ^= ((c>>1)&3)
    extern __shared__ _Float16 Ps_dyn[];              // [16 waves][16 q][32 key]

    _Float16* PsW = Ps_dyn + w * 512;

    // per-thread async staging geometry
    const int rowK = 2 * w + (L >> 5);                       // 0..31
    const int kSrcCol = (((L & 31) ^ (rowK & 7)) << 3);      // halves
    const int cV = 16 * w + (L >> 2);                        // 0..255
    const int vSrcCol = (((L & 3) ^ ((cV >> 1) & 3)) << 3);  // halves

    const _Float16* ktb = kt + (size_t)b * N_ * C_;
    const _Float16* vb  = v  + (size_t)b * C_ * N_;
    const _Float16* kSrc = ktb + (size_t)rowK * C_ + kSrcCol;
    const _Float16* vSrc = vb + (size_t)cV * N_ + vSrcCol;

    // Q B-frags (bits identical to old A-frags)
    halfx8 qfrag[8];
    {
        const _Float16* qrow = qt + ((size_t)b * N_ + q0 + w * 16 + lane15) * C_ + quad * 8;
#pragma unroll
        for (int cs = 0; cs < 8; ++cs)
            qfrag[cs] = __builtin_nontemporal_load((const halfx8*)(qrow + cs * 32));
    }

    floatx4 o_acc[16];
#pragma unroll
    for (int i = 0; i < 16; ++i) o_acc[i] = (floatx4){0.f, 0.f, 0.f, 0.f};
    float m_r = -1e30f, l_r = 0.f;

    const int kbeg = ks * 1024;
    const int swK = lane15 & 7;
    const int swV = (lane15 >> 1) & 3;

    // prologue: stage tile 0 into buf0
    async_copy16(kSrc + (size_t)kbeg * C_, (char*)&Kb0[0][0] + w * 1024);
    async_copy16(vSrc + kbeg,              (char*)&Vb0[0][0] + w * 1024);
    __syncthreads();

    int cur = 0;
    for (int it = 0; it < 32; ++it) {
        // issue async loads for next tile into the other buffer
        if (it < 31) {
            const int kn = kbeg + (it + 1) * TK;
            char* kd = (char*)(cur ? &Kb0[0][0] : &Kb1[0][0]) + w * 1024;
            char* vd = (char*)(cur ? &Vb0[0][0] : &Vb1[0][0]) + w * 1024;
            async_copy16(kSrc + (size_t)kn * C_, kd);
            async_copy16(vSrc + kn, vd);
        }
        const _Float16* Kc = cur ? &Kb1[0][0] : &Kb0[0][0];
        const _Float16* Vc = cur ? &Vb1[0][0] : &Vb0[0][0];

        // ---- S^T = K Q : D[key_local][q], row = quad*4+r, col = lane15 ----
        floatx4 s_acc[2];
        s_acc[0] = (floatx4){0.f, 0.f, 0.f, 0.f};
        s_acc[1] = (floatx4){0.f, 0.f, 0.f, 0.f};
#pragma unroll
        for (int t = 0; t < 2; ++t) {
            const _Float16* kr = Kc + (t * 16 + lane15) * 256;
#pragma unroll
            for (int cs = 0; cs < 8; ++cs) {
                const int pch = (quad + 4 * cs) ^ swK;
                halfx8 kf = *(const halfx8*)(kr + pch * 8);
                s_acc[t] = __builtin_amdgcn_mfma_f32_16x16x32_f16(kf, qfrag[cs], s_acc[t], 0, 0, 0);
            }
        }

        // ---- per-lane online softmax (q = lane15; 8 keys in regs) ----
        float rmax = fmaxf(fmaxf(fmaxf(s_acc[0][0], s_acc[0][1]), fmaxf(s_acc[0][2], s_acc[0][3])),
                           fmaxf(fmaxf(s_acc[1][0], s_acc[1][1]), fmaxf(s_acc[1][2], s_acc[1][3])));
        rmax = fmaxf(rmax, __shfl_xor(rmax, 16));
        rmax = fmaxf(rmax, __shfl_xor(rmax, 32));
        float mn = fmaxf(m_r, rmax);
        float alpha = __expf(m_r - mn);
        m_r = mn;
        float p0[4], p1[4];
        float psum = 0.f;
#pragma unroll
        for (int r = 0; r < 4; ++r) {
            p0[r] = __expf(s_acc[0][r] - mn);
            p1[r] = __expf(s_acc[1][r] - mn);
            psum += p0[r] + p1[r];
        }
        psum += __shfl_xor(psum, 16);
        psum += __shfl_xor(psum, 32);
        l_r = l_r * alpha + psum;

        // ---- P -> LDS (wave-local, packed b64): Ps[q=lane15][key] ----
        union { _Float16 h[4]; unsigned long long u64; } pk0, pk1;
#pragma unroll
        for (int r = 0; r < 4; ++r) { pk0.h[r] = (_Float16)p0[r]; pk1.h[r] = (_Float16)p1[r]; }
        *(unsigned long long*)(PsW + lane15 * 32 + quad * 4)      = pk0.u64;
        *(unsigned long long*)(PsW + lane15 * 32 + 16 + quad * 4) = pk1.u64;

        // ---- O *= alpha (lane-local); O += V P^T ----
#pragma unroll
        for (int i = 0; i < 16; ++i) o_acc[i] *= alpha;
        halfx8 pfrag = *(const halfx8*)(PsW + lane15 * 32 + quad * 8);  // B[k=key][n=q]
#pragma unroll
        for (int ct = 0; ct < 16; ++ct) {
            const int c = ct * 16 + lane15;
            halfx8 vf = *(const halfx8*)(Vc + c * 32 + ((quad ^ swV) * 8));  // A[m=c][k=key]
            o_acc[ct] = __builtin_amdgcn_mfma_f32_16x16x32_f16(vf, pfrag, o_acc[ct], 0, 0, 0);
        }

        __syncthreads();   // drains vmcnt (async tile landed) + all reads of cur done
        cur ^= 1;
    }

    // ---- store partials (r7-proven per-lane NT stores) ----
    const size_t pbase = (size_t)((b * 16 + qt_i) * 4 + ks);
    _Float16* ob = O_part + (pbase * 256 + (size_t)(w * 16 + lane15)) * 256;
#pragma unroll
    for (int ct = 0; ct < 16; ++ct) {
        union { _Float16 h[4]; unsigned long long u64; } pk;
#pragma unroll
        for (int r = 0; r < 4; ++r) pk.h[r] = (_Float16)o_acc[ct][r];
        __builtin_nontemporal_store(pk.u64, (unsigned long long*)(ob + ct * 16 + quad * 4));
    }
    if (quad == 0) {
        m_part[pbase * 256 + w * 16 + lane15] = m_r;
        l_part[pbase * 256 + w * 16 + lane15] = l_r;
    }
}

// ---------------- combine partials + epilogue (r7-proven) ----------------
__global__ __launch_bounds__(256) void reduce_kernel(
    const void* __restrict__ x_raw,
    const _Float16* __restrict__ O_part, // [b][qt16][ks4][q256][c256]
    const float* __restrict__ m_part,
    const float* __restrict__ l_part,
    const void* __restrict__ gamma_p,
    void* __restrict__ out,
    const int* __restrict__ flag) {
    const int isf32 = *flag;
    const int b = blockIdx.y;
    const int tid = threadIdx.x;
    const int q = tid & 63;
    const int wv = tid >> 6;
    const int n = blockIdx.x * 64 + q;
    const int qt_i = n >> 8;
    const int qq = n & 255;

    const size_t sbase = (size_t)(b * 16 + qt_i) * 4;
    float m0 = m_part[(sbase + 0) * 256 + qq], m1 = m_part[(sbase + 1) * 256 + qq],
          m2 = m_part[(sbase + 2) * 256 + qq], m3 = m_part[(sbase + 3) * 256 + qq];
    float l0 = l_part[(sbase + 0) * 256 + qq], l1 = l_part[(sbase + 1) * 256 + qq],
          l2 = l_part[(sbase + 2) * 256 + qq], l3 = l_part[(sbase + 3) * 256 + qq];
    float M = fmaxf(fmaxf(m0, m1), fmaxf(m2, m3));
    float w0 = __expf(m0 - M), w1 = __expf(m1 - M), w2 = __expf(m2 - M), w3 = __expf(m3 - M);
    float denom = w0 * l0 + w1 * l1 + w2 * l2 + w3 * l3;
    float g = isf32 ? ((const float*)gamma_p)[0] : bf16_to_f(((const uint16_t*)gamma_p)[0]);
    float s = g / denom;

    const _Float16* o0 = O_part + sbase * 65536 + (size_t)qq * 256;
#pragma unroll
    for (int ch = 0; ch < 8; ++ch) {
        const int c0 = wv * 64 + ch * 8;
        halfx8 a     = __builtin_nontemporal_load((const halfx8*)(o0 + c0));
        halfx8 bpart = __builtin_nontemporal_load((const halfx8*)(o0 + 65536 + c0));
        halfx8 cpart = __builtin_nontemporal_load((const halfx8*)(o0 + 131072 + c0));
        halfx8 dpart = __builtin_nontemporal_load((const halfx8*)(o0 + 196608 + c0));
#pragma unroll
        for (int j = 0; j < 8; ++j) {
            float acc = w0 * (float)a[j] + w1 * (float)bpart[j]
                      + w2 * (float)cpart[j] + w3 * (float)dpart[j];
            size_t off = ((size_t)b * 256 + c0 + j) * 4096 + n;
            float xv = isf32 ? __builtin_nontemporal_load((const float*)x_raw + off)
                             : bf16_to_f(((const uint16_t*)x_raw)[off]);
            float val = s * acc + xv;
            if (isf32) __builtin_nontemporal_store(val, (float*)out + off);
            else ((uint16_t*)out)[off] = f_to_bf16(val);
        }
    }
}

// ---------------- fallback: monolithic attn (small ws) ----------------
__global__ __launch_bounds__(256, 2) void attn_full_kernel(
    const void* __restrict__ x_raw,
    const _Float16* __restrict__ qt,
    const _Float16* __restrict__ kt,
    const _Float16* __restrict__ v,
    const void* __restrict__ gamma_p,
    void* __restrict__ out,
    const int* __restrict__ flag) {
    const int isf32 = *flag;
    const int b = blockIdx.y;
    const int q0 = blockIdx.x * 64;
    const int tid = threadIdx.x;
    const int w = tid >> 6;
    const int L = tid & 63;
    const int lane15 = L & 15;
    const int quad = L >> 4;

    __shared__ _Float16 Kt_s[TK][260];
    __shared__ _Float16 Vs[C_][36];
    __shared__ _Float16 Ps[4][16][36];
    __shared__ float alpha_s[4][16];
    __shared__ float l_s[4][16];

    halfx8 qfrag[8];
    {
        const _Float16* qrow = qt + ((size_t)b * N_ + q0 + w * 16 + lane15) * C_ + quad * 8;
#pragma unroll
        for (int cs = 0; cs < 8; ++cs) qfrag[cs] = *(const halfx8*)(qrow + cs * 32);
    }
    floatx4 o_acc[16];
#pragma unroll
    for (int i = 0; i < 16; ++i) o_acc[i] = (floatx4){0.f, 0.f, 0.f, 0.f};
    float m_r[4], l_r[4];
#pragma unroll
    for (int r = 0; r < 4; ++r) { m_r[r] = -1e30f; l_r[r] = 0.f; }
    const _Float16* ktb = kt + (size_t)b * N_ * C_;
    const _Float16* vb  = v  + (size_t)b * C_ * N_;

    for (int k0 = 0; k0 < N_; k0 += TK) {
#pragma unroll
        for (int p = 0; p < 4; ++p) {
            int idx = p * 256 + tid;
            int key = idx >> 5, ch = idx & 31;
            *(halfx8*)(&Kt_s[key][ch * 8]) =
                *(const halfx8*)(ktb + (size_t)(k0 + key) * C_ + ch * 8);
        }
#pragma unroll
        for (int p = 0; p < 4; ++p) {
            int idx = p * 256 + tid;
            int c = idx >> 2, ch = idx & 3;
            *(halfx8*)(&Vs[c][ch * 8]) =
                *(const halfx8*)(vb + (size_t)c * N_ + k0 + ch * 8);
        }
        __syncthreads();
        floatx4 s_acc[2];
        s_acc[0] = (floatx4){0.f, 0.f, 0.f, 0.f};
        s_acc[1] = (floatx4){0.f, 0.f, 0.f, 0.f};
#pragma unroll
        for (int ktile = 0; ktile < 2; ++ktile) {
            const _Float16* krow = &Kt_s[ktile * 16 + lane15][quad * 8];
#pragma unroll
            for (int cs = 0; cs < 8; ++cs) {
                halfx8 bf = *(const halfx8*)(krow + cs * 32);
                s_acc[ktile] = __builtin_amdgcn_mfma_f32_16x16x32_f16(qfrag[cs], bf, s_acc[ktile], 0, 0, 0);
            }
        }
        float rmax[4], psum[4], p0[4], p1[4], alpha[4];
#pragma unroll
        for (int r = 0; r < 4; ++r) rmax[r] = fmaxf(s_acc[0][r], s_acc[1][r]);
#pragma unroll
        for (int mask = 1; mask <= 8; mask <<= 1)
#pragma unroll
            for (int r = 0; r < 4; ++r) rmax[r] = fmaxf(rmax[r], __shfl_xor(rmax[r], mask));
#pragma unroll
        for (int r = 0; r < 4; ++r) {
            float mn = fmaxf(m_r[r], rmax[r]);
            alpha[r] = __expf(m_r[r] - mn);
            m_r[r] = mn;
            p0[r] = __expf(s_acc[0][r] - mn);
            p1[r] = __expf(s_acc[1][r] - mn);
            psum[r] = p0[r] + p1[r];
        }
#pragma unroll
        for (int mask = 1; mask <= 8; mask <<= 1)
#pragma unroll
            for (int r = 0; r < 4; ++r) psum[r] += __shfl_xor(psum[r], mask);
#pragma unroll
        for (int r = 0; r < 4; ++r) l_r[r] = l_r[r] * alpha[r] + psum[r];
#pragma unroll
        for (int r = 0; r < 4; ++r) {
            Ps[w][quad * 4 + r][lane15]      = (_Float16)p0[r];
            Ps[w][quad * 4 + r][16 + lane15] = (_Float16)p1[r];
        }
        if (lane15 == 0) {
#pragma unroll
            for (int r = 0; r < 4; ++r) alpha_s[w][quad * 4 + r] = alpha[r];
        }
        __syncthreads();
        float av = alpha_s[w][lane15];
#pragma unroll
        for (int i = 0; i < 16; ++i) {
            o_acc[i][0] *= av; o_acc[i][1] *= av; o_acc[i][2] *= av; o_acc[i][3] *= av;
        }
        halfx8 pfrag = *(const halfx8*)(&Ps[w][lane15][quad * 8]);
#pragma unroll
        for (int ct = 0; ct < 16; ++ct) {
            halfx8 vf = *(const halfx8*)(&Vs[ct * 16 + lane15][quad * 8]);
            o_acc[ct] = __builtin_amdgcn_mfma_f32_16x16x32_f16(vf, pfrag, o_acc[ct], 0, 0, 0);
        }
        __syncthreads();
    }
    if (lane15 == 0) {
#pragma unroll
        for (int r = 0; r < 4; ++r) l_s[w][quad * 4 + r] = l_r[r];
    }
    __syncthreads();
    float linv = 1.0f / l_s[w][lane15];
    float g = isf32 ? ((const float*)gamma_p)[0] : bf16_to_f(((const uint16_t*)gamma_p)[0]);
    const int n_out = q0 + w * 16 + lane15;
#pragma unroll
    for (int ct = 0; ct < 16; ++ct)
#pragma unroll
        for (int r = 0; r < 4; ++r) {
            int c = ct * 16 + quad * 4 + r;
            size_t off = ((size_t)b * C_ + c) * N_ + n_out;
            float val = g * o_acc[ct][r] * linv +
                        (isf32 ? ((const float*)x_raw)[off] : bf16_to_f(((const uint16_t*)x_raw)[off]));
            if (isf32) ((float*)out)[off] = val;
            else ((uint16_t*)out)[off] = f_to_bf16(val);
        }
}

// ---------------- launcher ----------------
extern "C" void kernel_launch(void* const* d_in, const int* in_sizes, int n_in,
                              void* d_out, int out_size, void* d_ws, size_t ws_size,
                              hipStream_t stream) {
    const void* x  = d_in[0];
    const void* wq = d_in[1];
    const void* wk = d_in[2];
    const void* wv = d_in[3];
    const void* gm = d_in[4];

    char* ws = (char*)d_ws;
    int* flag    = (int*)ws;
    _Float16* wf = (_Float16*)(ws + 4096);
    size_t o0 = 4096 + 393216;
    _Float16* qt = (_Float16*)(ws + o0);
    _Float16* kt = (_Float16*)(ws + o0 + 8388608);
    _Float16* v  = (_Float16*)(ws + o0 + 2 * 8388608);
    size_t o1 = o0 + 3 * 8388608;                       // 25,563,136
    _Float16* opart = (_Float16*)(ws + o1);             // 33,554,432 B
    float* mpart = (float*)(ws + o1 + 33554432);        // 262,144 B
    float* lpart = (float*)(ws + o1 + 33554432 + 262144);
    const size_t need = o1 + 33554432 + 2 * 262144;     // ~59.6 MB

    sniff_kernel<<<dim3(1), dim3(256), 0, stream>>>((const uint16_t*)wq, flag);
    wconv_kernel<<<dim3(768), dim3(256), 0, stream>>>(wq, wk, wv, wf, flag);
    proj_kernel<<<dim3(64, 4, 3), dim3(256), 0, stream>>>(x, wf, qt, kt, v, flag);
    if (ws_size >= need) {
        attn_kernel<<<dim3(256), dim3(1024), 16384, stream>>>(qt, kt, v, opart, mpart, lpart);
        reduce_kernel<<<dim3(64, 4), dim3(256), 0, stream>>>(x, opart, mpart, lpart, gm, d_out, flag);
    } else {
        attn_full_kernel<<<dim3(64, 4), dim3(256), 0, stream>>>(x, qt, kt, v, gm, d_out, flag);
    }
}

// Round 10
// 265.278 us; speedup vs baseline: 2.3026x; 1.0958x over previous
//
#include <hip/hip_runtime.h>
#include <stdint.h>

#define B_ 4
#define C_ 256
#define N_ 4096
#define TK 32

using floatx4 = __attribute__((ext_vector_type(4))) float;
using halfx8  = __attribute__((ext_vector_type(8))) _Float16;

__device__ __forceinline__ float bf16_to_f(uint16_t u) {
    union { uint32_t u; float f; } c; c.u = ((uint32_t)u) << 16; return c.f;
}
__device__ __forceinline__ uint16_t f_to_bf16(float f) {
    union { float f; uint32_t u; } c; c.f = f;
    uint32_t u = c.u;
    u += 0x7FFFu + ((u >> 16) & 1u);   // RNE
    return (uint16_t)(u >> 16);
}

__device__ __forceinline__ void async_copy16(const void* g, void* l) {
    __builtin_amdgcn_global_load_lds(
        (const __attribute__((address_space(1))) void*)g,
        (__attribute__((address_space(3))) void*)l, 16, 0, 0);
}

// ---------------- sniff input dtype (1 = f32, 0 = bf16) ----------------
__global__ void sniff_kernel(const uint16_t* __restrict__ wq_u16, int* __restrict__ flag) {
    __shared__ int cnt;
    if (threadIdx.x == 0) cnt = 0;
    __syncthreads();
    int local = 0;
    for (int i = threadIdx.x; i < 8192; i += 256) {
        int e = (wq_u16[i] >> 7) & 0xFF;
        if (e >= 132) local++;
    }
    atomicAdd(&cnt, local);
    __syncthreads();
    if (threadIdx.x == 0) *flag = (cnt > 64) ? 1 : 0;
}

// ---------------- W -> f16 ----------------
__global__ void wconv_kernel(const void* __restrict__ wq,
                             const void* __restrict__ wk,
                             const void* __restrict__ wv,
                             _Float16* __restrict__ wf,
                             const int* __restrict__ flag) {
    const int isf32 = *flag;
    int idx = blockIdx.x * 256 + threadIdx.x;
    int mat = idx >> 16;
    int off = idx & 65535;
    const void* src = (mat == 0) ? wq : ((mat == 1) ? wk : wv);
    float v = isf32 ? ((const float*)src)[off] : bf16_to_f(((const uint16_t*)src)[off]);
    wf[idx] = (_Float16)v;
}

// ---------------- QKV projection (MFMA f16), mat = blockIdx.z ----------------
__global__ __launch_bounds__(256) void proj_kernel(
    const void* __restrict__ x_raw,
    const _Float16* __restrict__ wf,
    _Float16* __restrict__ qt,           // (B,N,C)
    _Float16* __restrict__ kt,           // (B,N,C)
    _Float16* __restrict__ v,            // (B,C,N)
    const int* __restrict__ flag) {
    const int isf32 = *flag;
    const int b = blockIdx.y;
    const int mat = blockIdx.z;
    const int n0 = blockIdx.x * 64;
    const int tid = threadIdx.x;
    const int w = tid >> 6;
    const int L = tid & 63;
    const int lane15 = L & 15;
    const int quad = L >> 4;
    const int n = n0 + w * 16 + lane15;

    halfx8 bfrag[8];
    const size_t xbase = (size_t)b * C_ * N_;
    if (isf32) {
        const float* xb = (const float*)x_raw + xbase;
#pragma unroll
        for (int cs = 0; cs < 8; ++cs) {
            const int cbase = cs * 32 + quad * 8;
            halfx8 f;
#pragma unroll
            for (int j = 0; j < 8; ++j)
                f[j] = (_Float16)xb[(size_t)(cbase + j) * N_ + n];
            bfrag[cs] = f;
        }
    } else {
        const uint16_t* xb = (const uint16_t*)x_raw + xbase;
#pragma unroll
        for (int cs = 0; cs < 8; ++cs) {
            const int cbase = cs * 32 + quad * 8;
            halfx8 f;
#pragma unroll
            for (int j = 0; j < 8; ++j)
                f[j] = (_Float16)bf16_to_f(xb[(size_t)(cbase + j) * N_ + n]);
            bfrag[cs] = f;
        }
    }

    const _Float16* wm = wf + mat * (C_ * C_);
#pragma unroll 4
    for (int ot = 0; ot < 16; ++ot) {
        const int obase = ot * 16;
        floatx4 acc = {0.f, 0.f, 0.f, 0.f};
        const _Float16* wrow = wm + (size_t)(obase + lane15) * C_ + quad * 8;
#pragma unroll
        for (int cs = 0; cs < 8; ++cs) {
            halfx8 af = *(const halfx8*)(wrow + cs * 32);
            acc = __builtin_amdgcn_mfma_f32_16x16x32_f16(af, bfrag[cs], acc, 0, 0, 0);
        }
        if (mat < 2) {
            _Float16* dst = (mat == 0 ? qt : kt) +
                            ((size_t)b * N_ + n) * C_ + obase + quad * 4;
            union { _Float16 h[4]; unsigned long long u64; } pk;
#pragma unroll
            for (int r = 0; r < 4; ++r) pk.h[r] = (_Float16)acc[r];
            *(unsigned long long*)dst = pk.u64;
        } else {
            _Float16* dst = v + ((size_t)b * C_ + obase + quad * 4) * N_ + n;
#pragma unroll
            for (int r = 0; r < 4; ++r) dst[(size_t)r * N_] = (_Float16)acc[r];
        }
    }
}

// ---------------- flash attention: Qtile=256, 8 waves x 32q, async dbuf ----------------
// 256 blocks x 512 thr, 1 block/CU. Each wave owns TWO 16-q column tiles: K and V
// fragments are read from LDS once and MFMA'd twice -> per-CU LDS traffic halves
// vs r9 (the measured bottleneck). Ps stride 40 halves fixes the 8-way banking.
__global__ __launch_bounds__(512, 2) void attn_kernel(
    const _Float16* __restrict__ qt,     // (B,N,C)
    const _Float16* __restrict__ kt,     // (B,N,C)
    const _Float16* __restrict__ v,      // (B,C,N)
    _Float16* __restrict__ O_part,       // [b][qt16][ks4][q256][c256] f16
    float* __restrict__ m_part,          // [b][qt16][ks4][q256]
    float* __restrict__ l_part) {
    const int l = blockIdx.x;
    const int combo = (l & 7) | ((l >> 7) << 3);
    const int qt_i = (l >> 3) & 15;
    const int b = combo >> 2;
    const int ks = combo & 3;
    const int q0 = qt_i * 256;
    const int tid = threadIdx.x;
    const int w = tid >> 6;              // 0..7
    const int L = tid & 63;
    const int lane15 = L & 15;
    const int quad = L >> 4;

    __shared__ _Float16 Kb0[32][256], Kb1[32][256];   // [key][c], chunk ^= (key&7)
    __shared__ _Float16 Vb0[256][32], Vb1[256][32];   // [c][key], chunk ^= ((c>>1)&3)
    extern __shared__ _Float16 Ps_dyn[];              // 8 waves x 32 q x 40 (20 KB)

    _Float16* PsW = Ps_dyn + w * 1280;

    // async staging geometry: 2 slices (p) x 512 thr cover 1024 16B-chunks per array
    const int rowK = 2 * w + (L >> 5);                      // 0..15 (+16 for p=1)
    const int kCol = (((L & 31) ^ (rowK & 7)) << 3);        // halves; (rowK+16)&7 == rowK&7
    const int cV   = 16 * w + (L >> 2);                     // 0..127 (+128 for p=1)
    const int vCol = (((L & 3) ^ ((L >> 3) & 3)) << 3);     // (cV>>1)&3 == (L>>3)&3

    const _Float16* ktb = kt + (size_t)b * N_ * C_;
    const _Float16* vb  = v  + (size_t)b * C_ * N_;
    const _Float16* kSrc0 = ktb + (size_t)rowK * C_ + kCol;
    const _Float16* kSrc1 = ktb + (size_t)(rowK + 16) * C_ + kCol;
    const _Float16* vSrc0 = vb + (size_t)cV * N_ + vCol;
    const _Float16* vSrc1 = vb + (size_t)(cV + 128) * N_ + vCol;
    const int ldsOff = w * 1024;                            // bytes within each 8 KB slice

    // Q B-frags, two 16-q tiles: q = q0 + w*32 + j*16 + lane15
    halfx8 qfrag[2][8];
#pragma unroll
    for (int j = 0; j < 2; ++j) {
        const _Float16* qrow = qt + ((size_t)b * N_ + q0 + w * 32 + j * 16 + lane15) * C_ + quad * 8;
#pragma unroll
        for (int cs = 0; cs < 8; ++cs)
            qfrag[j][cs] = __builtin_nontemporal_load((const halfx8*)(qrow + cs * 32));
    }

    floatx4 o_acc[2][16];
#pragma unroll
    for (int j = 0; j < 2; ++j)
#pragma unroll
        for (int i = 0; i < 16; ++i) o_acc[j][i] = (floatx4){0.f, 0.f, 0.f, 0.f};
    float m_r[2] = {-1e30f, -1e30f}, l_r[2] = {0.f, 0.f};

    const int kbeg = ks * 1024;
    const int swK = lane15 & 7;
    const int swV = (lane15 >> 1) & 3;

    // prologue: stage tile 0 into buf0
    async_copy16(kSrc0 + (size_t)kbeg * C_, (char*)&Kb0[0][0] + ldsOff);
    async_copy16(kSrc1 + (size_t)kbeg * C_, (char*)&Kb0[0][0] + 8192 + ldsOff);
    async_copy16(vSrc0 + kbeg,              (char*)&Vb0[0][0] + ldsOff);
    async_copy16(vSrc1 + kbeg,              (char*)&Vb0[0][0] + 8192 + ldsOff);
    __syncthreads();

    int cur = 0;
    for (int it = 0; it < 32; ++it) {
        if (it < 31) {
            const int kn = kbeg + (it + 1) * TK;
            char* kd = (char*)(cur ? &Kb0[0][0] : &Kb1[0][0]);
            char* vd = (char*)(cur ? &Vb0[0][0] : &Vb1[0][0]);
            async_copy16(kSrc0 + (size_t)kn * C_, kd + ldsOff);
            async_copy16(kSrc1 + (size_t)kn * C_, kd + 8192 + ldsOff);
            async_copy16(vSrc0 + kn, vd + ldsOff);
            async_copy16(vSrc1 + kn, vd + 8192 + ldsOff);
        }
        const _Float16* Kc = cur ? &Kb1[0][0] : &Kb0[0][0];
        const _Float16* Vc = cur ? &Vb1[0][0] : &Vb0[0][0];

        // ---- S^T = K Q : D[key_local][q]; K frag shared by both q tiles ----
        floatx4 s_acc[2][2];
#pragma unroll
        for (int j = 0; j < 2; ++j)
#pragma unroll
            for (int t = 0; t < 2; ++t) s_acc[j][t] = (floatx4){0.f, 0.f, 0.f, 0.f};
#pragma unroll
        for (int t = 0; t < 2; ++t) {
            const _Float16* kr = Kc + (t * 16 + lane15) * 256;
#pragma unroll
            for (int cs = 0; cs < 8; ++cs) {
                const int pch = (quad + 4 * cs) ^ swK;
                halfx8 kf = *(const halfx8*)(kr + pch * 8);
                s_acc[0][t] = __builtin_amdgcn_mfma_f32_16x16x32_f16(kf, qfrag[0][cs], s_acc[0][t], 0, 0, 0);
                s_acc[1][t] = __builtin_amdgcn_mfma_f32_16x16x32_f16(kf, qfrag[1][cs], s_acc[1][t], 0, 0, 0);
            }
        }

        // ---- per-lane online softmax for both q tiles (q = lane15 of tile j) ----
        float alpha[2];
#pragma unroll
        for (int j = 0; j < 2; ++j) {
            float rmax = fmaxf(
                fmaxf(fmaxf(s_acc[j][0][0], s_acc[j][0][1]), fmaxf(s_acc[j][0][2], s_acc[j][0][3])),
                fmaxf(fmaxf(s_acc[j][1][0], s_acc[j][1][1]), fmaxf(s_acc[j][1][2], s_acc[j][1][3])));
            rmax = fmaxf(rmax, __shfl_xor(rmax, 16));
            rmax = fmaxf(rmax, __shfl_xor(rmax, 32));
            float mn = fmaxf(m_r[j], rmax);
            alpha[j] = __expf(m_r[j] - mn);
            m_r[j] = mn;
            float p0[4], p1[4];
            float psum = 0.f;
#pragma unroll
            for (int r = 0; r < 4; ++r) {
                p0[r] = __expf(s_acc[j][0][r] - mn);
                p1[r] = __expf(s_acc[j][1][r] - mn);
                psum += p0[r] + p1[r];
            }
            psum += __shfl_xor(psum, 16);
            psum += __shfl_xor(psum, 32);
            l_r[j] = l_r[j] * alpha[j] + psum;

            union { _Float16 h[4]; unsigned long long u64; } pk0, pk1;
#pragma unroll
            for (int r = 0; r < 4; ++r) { pk0.h[r] = (_Float16)p0[r]; pk1.h[r] = (_Float16)p1[r]; }
            _Float16* prow = PsW + (j * 16 + lane15) * 40;
            *(unsigned long long*)(prow + quad * 4)      = pk0.u64;
            *(unsigned long long*)(prow + 16 + quad * 4) = pk1.u64;
        }

        // ---- O *= alpha; O += V P^T (V frag shared by both q tiles) ----
#pragma unroll
        for (int j = 0; j < 2; ++j)
#pragma unroll
            for (int i = 0; i < 16; ++i) o_acc[j][i] *= alpha[j];
        halfx8 pfrag0 = *(const halfx8*)(PsW + lane15 * 40 + quad * 8);
        halfx8 pfrag1 = *(const halfx8*)(PsW + (16 + lane15) * 40 + quad * 8);
#pragma unroll
        for (int ct = 0; ct < 16; ++ct) {
            const int c = ct * 16 + lane15;
            halfx8 vf = *(const halfx8*)(Vc + c * 32 + ((quad ^ swV) * 8));
            o_acc[0][ct] = __builtin_amdgcn_mfma_f32_16x16x32_f16(vf, pfrag0, o_acc[0][ct], 0, 0, 0);
            o_acc[1][ct] = __builtin_amdgcn_mfma_f32_16x16x32_f16(vf, pfrag1, o_acc[1][ct], 0, 0, 0);
        }

        __syncthreads();   // drains vmcnt (prefetch landed) + all reads of cur done
        cur ^= 1;
    }

    // ---- store partials ----
    const size_t pbase = (size_t)((b * 16 + qt_i) * 4 + ks);
#pragma unroll
    for (int j = 0; j < 2; ++j) {
        _Float16* ob = O_part + (pbase * 256 + (size_t)(w * 32 + j * 16 + lane15)) * 256;
#pragma unroll
        for (int ct = 0; ct < 16; ++ct) {
            union { _Float16 h[4]; unsigned long long u64; } pk;
#pragma unroll
            for (int r = 0; r < 4; ++r) pk.h[r] = (_Float16)o_acc[j][ct][r];
            __builtin_nontemporal_store(pk.u64, (unsigned long long*)(ob + ct * 16 + quad * 4));
        }
        if (quad == 0) {
            m_part[pbase * 256 + w * 32 + j * 16 + lane15] = m_r[j];
            l_part[pbase * 256 + w * 32 + j * 16 + lane15] = l_r[j];
        }
    }
}

// ---------------- combine partials + epilogue (r7/r9-proven) ----------------
__global__ __launch_bounds__(256) void reduce_kernel(
    const void* __restrict__ x_raw,
    const _Float16* __restrict__ O_part, // [b][qt16][ks4][q256][c256]
    const float* __restrict__ m_part,
    const float* __restrict__ l_part,
    const void* __restrict__ gamma_p,
    void* __restrict__ out,
    const int* __restrict__ flag) {
    const int isf32 = *flag;
    const int b = blockIdx.y;
    const int tid = threadIdx.x;
    const int q = tid & 63;
    const int wv = tid >> 6;
    const int n = blockIdx.x * 64 + q;
    const int qt_i = n >> 8;
    const int qq = n & 255;

    const size_t sbase = (size_t)(b * 16 + qt_i) * 4;
    float m0 = m_part[(sbase + 0) * 256 + qq], m1 = m_part[(sbase + 1) * 256 + qq],
          m2 = m_part[(sbase + 2) * 256 + qq], m3 = m_part[(sbase + 3) * 256 + qq];
    float l0 = l_part[(sbase + 0) * 256 + qq], l1 = l_part[(sbase + 1) * 256 + qq],
          l2 = l_part[(sbase + 2) * 256 + qq], l3 = l_part[(sbase + 3) * 256 + qq];
    float M = fmaxf(fmaxf(m0, m1), fmaxf(m2, m3));
    float w0 = __expf(m0 - M), w1 = __expf(m1 - M), w2 = __expf(m2 - M), w3 = __expf(m3 - M);
    float denom = w0 * l0 + w1 * l1 + w2 * l2 + w3 * l3;
    float g = isf32 ? ((const float*)gamma_p)[0] : bf16_to_f(((const uint16_t*)gamma_p)[0]);
    float s = g / denom;

    const _Float16* o0 = O_part + sbase * 65536 + (size_t)qq * 256;
#pragma unroll
    for (int ch = 0; ch < 8; ++ch) {
        const int c0 = wv * 64 + ch * 8;
        halfx8 a     = __builtin_nontemporal_load((const halfx8*)(o0 + c0));
        halfx8 bpart = __builtin_nontemporal_load((const halfx8*)(o0 + 65536 + c0));
        halfx8 cpart = __builtin_nontemporal_load((const halfx8*)(o0 + 131072 + c0));
        halfx8 dpart = __builtin_nontemporal_load((const halfx8*)(o0 + 196608 + c0));
#pragma unroll
        for (int j = 0; j < 8; ++j) {
            float acc = w0 * (float)a[j] + w1 * (float)bpart[j]
                      + w2 * (float)cpart[j] + w3 * (float)dpart[j];
            size_t off = ((size_t)b * 256 + c0 + j) * 4096 + n;
            float xv = isf32 ? __builtin_nontemporal_load((const float*)x_raw + off)
                             : bf16_to_f(((const uint16_t*)x_raw)[off]);
            float val = s * acc + xv;
            if (isf32) __builtin_nontemporal_store(val, (float*)out + off);
            else ((uint16_t*)out)[off] = f_to_bf16(val);
        }
    }
}

// ---------------- fallback: monolithic attn (small ws) ----------------
__global__ __launch_bounds__(256, 2) void attn_full_kernel(
    const void* __restrict__ x_raw,
    const _Float16* __restrict__ qt,
    const _Float16* __restrict__ kt,
    const _Float16* __restrict__ v,
    const void* __restrict__ gamma_p,
    void* __restrict__ out,
    const int* __restrict__ flag) {
    const int isf32 = *flag;
    const int b = blockIdx.y;
    const int q0 = blockIdx.x * 64;
    const int tid = threadIdx.x;
    const int w = tid >> 6;
    const int L = tid & 63;
    const int lane15 = L & 15;
    const int quad = L >> 4;

    __shared__ _Float16 Kt_s[TK][260];
    __shared__ _Float16 Vs[C_][36];
    __shared__ _Float16 Ps[4][16][36];
    __shared__ float alpha_s[4][16];
    __shared__ float l_s[4][16];

    halfx8 qfrag[8];
    {
        const _Float16* qrow = qt + ((size_t)b * N_ + q0 + w * 16 + lane15) * C_ + quad * 8;
#pragma unroll
        for (int cs = 0; cs < 8; ++cs) qfrag[cs] = *(const halfx8*)(qrow + cs * 32);
    }
    floatx4 o_acc[16];
#pragma unroll
    for (int i = 0; i < 16; ++i) o_acc[i] = (floatx4){0.f, 0.f, 0.f, 0.f};
    float m_r[4], l_r[4];
#pragma unroll
    for (int r = 0; r < 4; ++r) { m_r[r] = -1e30f; l_r[r] = 0.f; }
    const _Float16* ktb = kt + (size_t)b * N_ * C_;
    const _Float16* vb  = v  + (size_t)b * C_ * N_;

    for (int k0 = 0; k0 < N_; k0 += TK) {
#pragma unroll
        for (int p = 0; p < 4; ++p) {
            int idx = p * 256 + tid;
            int key = idx >> 5, ch = idx & 31;
            *(halfx8*)(&Kt_s[key][ch * 8]) =
                *(const halfx8*)(ktb + (size_t)(k0 + key) * C_ + ch * 8);
        }
#pragma unroll
        for (int p = 0; p < 4; ++p) {
            int idx = p * 256 + tid;
            int c = idx >> 2, ch = idx & 3;
            *(halfx8*)(&Vs[c][ch * 8]) =
                *(const halfx8*)(vb + (size_t)c * N_ + k0 + ch * 8);
        }
        __syncthreads();
        floatx4 s_acc[2];
        s_acc[0] = (floatx4){0.f, 0.f, 0.f, 0.f};
        s_acc[1] = (floatx4){0.f, 0.f, 0.f, 0.f};
#pragma unroll
        for (int ktile = 0; ktile < 2; ++ktile) {
            const _Float16* krow = &Kt_s[ktile * 16 + lane15][quad * 8];
#pragma unroll
            for (int cs = 0; cs < 8; ++cs) {
                halfx8 bf = *(const halfx8*)(krow + cs * 32);
                s_acc[ktile] = __builtin_amdgcn_mfma_f32_16x16x32_f16(qfrag[cs], bf, s_acc[ktile], 0, 0, 0);
            }
        }
        float rmax[4], psum[4], p0[4], p1[4], alpha[4];
#pragma unroll
        for (int r = 0; r < 4; ++r) rmax[r] = fmaxf(s_acc[0][r], s_acc[1][r]);
#pragma unroll
        for (int mask = 1; mask <= 8; mask <<= 1)
#pragma unroll
            for (int r = 0; r < 4; ++r) rmax[r] = fmaxf(rmax[r], __shfl_xor(rmax[r], mask));
#pragma unroll
        for (int r = 0; r < 4; ++r) {
            float mn = fmaxf(m_r[r], rmax[r]);
            alpha[r] = __expf(m_r[r] - mn);
            m_r[r] = mn;
            p0[r] = __expf(s_acc[0][r] - mn);
            p1[r] = __expf(s_acc[1][r] - mn);
            psum[r] = p0[r] + p1[r];
        }
#pragma unroll
        for (int mask = 1; mask <= 8; mask <<= 1)
#pragma unroll
            for (int r = 0; r < 4; ++r) psum[r] += __shfl_xor(psum[r], mask);
#pragma unroll
        for (int r = 0; r < 4; ++r) l_r[r] = l_r[r] * alpha[r] + psum[r];
#pragma unroll
        for (int r = 0; r < 4; ++r) {
            Ps[w][quad * 4 + r][lane15]      = (_Float16)p0[r];
            Ps[w][quad * 4 + r][16 + lane15] = (_Float16)p1[r];
        }
        if (lane15 == 0) {
#pragma unroll
            for (int r = 0; r < 4; ++r) alpha_s[w][quad * 4 + r] = alpha[r];
        }
        __syncthreads();
        float av = alpha_s[w][lane15];
#pragma unroll
        for (int i = 0; i < 16; ++i) {
            o_acc[i][0] *= av; o_acc[i][1] *= av; o_acc[i][2] *= av; o_acc[i][3] *= av;
        }
        halfx8 pfrag = *(const halfx8*)(&Ps[w][lane15][quad * 8]);
#pragma unroll
        for (int ct = 0; ct < 16; ++ct) {
            halfx8 vf = *(const halfx8*)(&Vs[ct * 16 + lane15][quad * 8]);
            o_acc[ct] = __builtin_amdgcn_mfma_f32_16x16x32_f16(vf, pfrag, o_acc[ct], 0, 0, 0);
        }
        __syncthreads();
    }
    if (lane15 == 0) {
#pragma unroll
        for (int r = 0; r < 4; ++r) l_s[w][quad * 4 + r] = l_r[r];
    }
    __syncthreads();
    float linv = 1.0f / l_s[w][lane15];
    float g = isf32 ? ((const float*)gamma_p)[0] : bf16_to_f(((const uint16_t*)gamma_p)[0]);
    const int n_out = q0 + w * 16 + lane15;
#pragma unroll
    for (int ct = 0; ct < 16; ++ct)
#pragma unroll
        for (int r = 0; r < 4; ++r) {
            int c = ct * 16 + quad * 4 + r;
            size_t off = ((size_t)b * C_ + c) * N_ + n_out;
            float val = g * o_acc[ct][r] * linv +
                        (isf32 ? ((const float*)x_raw)[off] : bf16_to_f(((const uint16_t*)x_raw)[off]));
            if (isf32) ((float*)out)[off] = val;
            else ((uint16_t*)out)[off] = f_to_bf16(val);
        }
}

// ---------------- launcher ----------------
extern "C" void kernel_launch(void* const* d_in, const int* in_sizes, int n_in,
                              void* d_out, int out_size, void* d_ws, size_t ws_size,
                              hipStream_t stream) {
    const void* x  = d_in[0];
    const void* wq = d_in[1];
    const void* wk = d_in[2];
    const void* wv = d_in[3];
    const void* gm = d_in[4];

    char* ws = (char*)d_ws;
    int* flag    = (int*)ws;
    _Float16* wf = (_Float16*)(ws + 4096);
    size_t o0 = 4096 + 393216;
    _Float16* qt = (_Float16*)(ws + o0);
    _Float16* kt = (_Float16*)(ws + o0 + 8388608);
    _Float16* v  = (_Float16*)(ws + o0 + 2 * 8388608);
    size_t o1 = o0 + 3 * 8388608;                       // 25,563,136
    _Float16* opart = (_Float16*)(ws + o1);             // 33,554,432 B
    float* mpart = (float*)(ws + o1 + 33554432);        // 262,144 B
    float* lpart = (float*)(ws + o1 + 33554432 + 262144);
    const size_t need = o1 + 33554432 + 2 * 262144;     // ~59.6 MB

    sniff_kernel<<<dim3(1), dim3(256), 0, stream>>>((const uint16_t*)wq, flag);
    wconv_kernel<<<dim3(768), dim3(256), 0, stream>>>(wq, wk, wv, wf, flag);
    proj_kernel<<<dim3(64, 4, 3), dim3(256), 0, stream>>>(x, wf, qt, kt, v, flag);
    if (ws_size >= need) {
        attn_kernel<<<dim3(256), dim3(512), 20480, stream>>>(qt, kt, v, opart, mpart, lpart);
        reduce_kernel<<<dim3(64, 4), dim3(256), 0, stream>>>(x, opart, mpart, lpart, gm, d_out, flag);
    } else {
        attn_full_kernel<<<dim3(64, 4), dim3(256), 0, stream>>>(x, qt, kt, v, gm, d_out, flag);
    }
}